// Round 3
// 388.491 us; speedup vs baseline: 1.0244x; 1.0244x over previous
//
#include <hip/hip_runtime.h>
#include <hip/hip_bf16.h>
#include <cmath>

typedef unsigned short u16;
typedef __attribute__((ext_vector_type(8))) short short8;
typedef __attribute__((ext_vector_type(4))) float f32x4;
typedef __attribute__((ext_vector_type(4))) unsigned short u16x4;

#define AT_B 2
#define AT_T 2048
#define AT_H 16
#define AT_D 128
#define AT_M 2048
#define NROW (AT_B*AT_T)   // 4096
#define HD   (AT_H*AT_D)   // 2048

__device__ __forceinline__ u16 f2bf(float f) {
    union { float f; unsigned u; } v; v.f = f;
    unsigned u = v.u;
    unsigned r = u + 0x7fffu + ((u >> 16) & 1u);
    return (u16)(r >> 16);
}
__device__ __forceinline__ float bf2f(u16 h) {
    union { unsigned u; float f; } v; v.u = ((unsigned)h) << 16;
    return v.f;
}
__device__ __forceinline__ unsigned pack_bf2(float a, float b) {
    __hip_bfloat162 t = __float22bfloat162_rn(make_float2(a, b));
    union { __hip_bfloat162 h; unsigned u; } v; v.h = t;
    return v.u;
}

// async global->LDS DMA, 16B per lane. LDS dest = wave-uniform base + lane*16.
__device__ __forceinline__ void gload16(const u16* g, u16* l) {
    __builtin_amdgcn_global_load_lds(
        (const __attribute__((address_space(1))) void*)g,
        (__attribute__((address_space(3))) void*)l, 16, 0, 0);
}

// ---------------- elementwise cast fp32 -> bf16 (vec4) ----------------
__global__ void cast_bf16_k(const float* __restrict__ in, u16* __restrict__ out, int n4) {
    int i = blockIdx.x * 256 + threadIdx.x;
    if (i >= n4) return;
    float4 v = ((const float4*)in)[i];
    u16x4 o;
    o.x = f2bf(v.x); o.y = f2bf(v.y); o.z = f2bf(v.z); o.w = f2bf(v.w);
    ((u16x4*)out)[i] = o;
}

// ------------- QKV weight transpose-cast: 3 weights in one launch -------------
__global__ void tcast3_k(const float* __restrict__ wq, const float* __restrict__ wk,
                         const float* __restrict__ wv, u16* __restrict__ out) {
    __shared__ float tile[32][33];
    int bx = blockIdx.x, by = blockIdx.y, bz = blockIdx.z;
    int which = bz >> 4, h = bz & 15;
    const float* ip = (which == 0 ? wq : which == 1 ? wk : wv) + (size_t)h * AT_M * AT_D;
    u16* op = out + ((size_t)which * AT_H + h) * AT_M * AT_D;
    int tx = threadIdx.x, ty = threadIdx.y;
    #pragma unroll
    for (int j = 0; j < 32; j += 8)
        tile[ty + j][tx] = ip[(size_t)(by * 32 + ty + j) * AT_D + bx * 32 + tx];
    __syncthreads();
    #pragma unroll
    for (int j = 0; j < 32; j += 8)
        op[(size_t)(bx * 32 + ty + j) * AT_M + by * 32 + tx] = f2bf(tile[tx][ty + j]);
}

// ------------- transpose-cast: in[R][C] fp32 -> out[C][R] bf16 (w_ao) -------------
__global__ void tcast_k(const float* __restrict__ in, u16* __restrict__ out, int R, int C) {
    __shared__ float tile[32][33];
    int bx = blockIdx.x, by = blockIdx.y;
    int tx = threadIdx.x, ty = threadIdx.y;
    #pragma unroll
    for (int j = 0; j < 32; j += 8)
        tile[ty + j][tx] = in[(size_t)(by * 32 + ty + j) * C + bx * 32 + tx];
    __syncthreads();
    #pragma unroll
    for (int j = 0; j < 32; j += 8)
        out[(size_t)(bx * 32 + ty + j) * R + by * 32 + tx] = f2bf(tile[tx][ty + j]);
}

// ------------- batched transpose bf16 -> bf16: in[bz][R][C] -> out[bz][C][R] -------------
__global__ void tbf16_k(const u16* __restrict__ in, u16* __restrict__ out, int R, int C) {
    __shared__ u16 tile[32][33];
    int bx = blockIdx.x, by = blockIdx.y, bz = blockIdx.z;
    const u16* ip = in + (size_t)bz * R * C;
    u16* op = out + (size_t)bz * R * C;
    int tx = threadIdx.x, ty = threadIdx.y;
    #pragma unroll
    for (int j = 0; j < 32; j += 8)
        tile[ty + j][tx] = ip[(size_t)(by * 32 + ty + j) * C + bx * 32 + tx];
    __syncthreads();
    #pragma unroll
    for (int j = 0; j < 32; j += 8)
        op[(size_t)(bx * 32 + ty + j) * R + by * 32 + tx] = tile[tx][ty + j];
}

// ---------------- RoPE in place; q additionally scaled by 1/128 (muP) ----------------
__global__ void rope_k(u16* __restrict__ q, u16* __restrict__ k, int total) {
    int i = blockIdx.x * 256 + threadIdx.x;
    if (i >= total) return;
    int d = i & 63;
    int rest = i >> 6;                 // (b*T+t)*H + h
    int t = (rest >> 4) & (AT_T - 1);
    size_t base = (size_t)rest * 128;
    float freq = __expf(-(float)d * (9.210340371976184f / 64.0f)); // 10000^{-d/64}
    float ang = (float)t * freq;
    float s, c;
    sincosf(ang, &s, &c);
    const float qs = 0.0078125f;  // 1/128, exact
    float qe = bf2f(q[base + d]), qo = bf2f(q[base + d + 64]);
    q[base + d]      = f2bf((qe * c - qo * s) * qs);
    q[base + d + 64] = f2bf((qe * s + qo * c) * qs);
    float ke = bf2f(k[base + d]), ko = bf2f(k[base + d + 64]);
    k[base + d]      = f2bf(ke * c - ko * s);
    k[base + d + 64] = f2bf(ke * s + ko * c);
}

// =================================================================================
// 256x192-tile QKV GEMM, 512 threads (8 waves 2x4), per-wave output 128x48.
//   C_seg = A[M][K] * Bt[N][K]^T, segmented bf16 output (q|k|v each [M][2048]).
// Structure (DS-pipe relief vs 128^2 kernel):
//   - global_load_lds (16B) staging: zero ds_write instructions on the DS pipe
//   - involution chunk swizzle j^(r&7): linear LDS dest + pre-swizzled global src
//     + swizzled ds_read_b128 (rule 21 both-sides pattern; conflict-free, 2-way max)
//   - double-buffered LDS (112 KiB), stage-2-tiles-ahead, counted s_waitcnt vmcnt(7)
//     (never 0 in main loop) + raw s_barrier: prefetch stays in flight across barriers
// Per-CU ledger per K-tile: MFMA 384x4.85=1862cy vs DS 176x12=2112cy (was 2304 DS
// vs 1242 MFMA at 128^2). Grid 32x16=512 blocks = exactly 2 rounds of 256 CUs.
// =================================================================================
#define G_ASZ (256*64)
#define G_BSZ (192*64)
#define G_STRIDE (G_ASZ + G_BSZ)
__global__ __launch_bounds__(512, 2) void gemm256_qkv_k(
    const u16* __restrict__ A, const u16* __restrict__ Bt, u16* __restrict__ Cv,
    int M, int N, int K)
{
    __shared__ __align__(1024) u16 smem[2 * G_STRIDE];   // 112 KiB
    const int tid  = threadIdx.x;
    const int wave = tid >> 6, lane = tid & 63;
    const int quad = lane >> 4, l16 = lane & 15;
    const int wr = wave >> 2, wc = wave & 3;
    const int m0 = blockIdx.y * 256, n0 = blockIdx.x * 192;

    // staging geometry: lane covers (row rl within 8-row group, chunk c=lane&7)
    const int rl = lane >> 3;               // 0..7
    const int jc = (lane & 7) ^ rl;         // pre-swizzled source k-chunk
    const u16* ga = A  + (size_t)(m0 + wave * 8 + rl) * K + jc * 8;
    const u16* gb = Bt + (size_t)(n0 + wave * 8 + rl) * K + jc * 8;
    const int ldst = (wave * 64) * 8;       // u16 offset of this wave's first chunk

    f32x4 zero = {0.f, 0.f, 0.f, 0.f};
    f32x4 acc[8][3];
    #pragma unroll
    for (int i = 0; i < 8; i++)
        #pragma unroll
        for (int j = 0; j < 3; j++) acc[i][j] = zero;

    const int NT = K >> 6;

    // prologue: tiles 0 and 1 in flight, wait for tile 0 only
    {
        #pragma unroll
        for (int i = 0; i < 4; ++i) gload16(ga + (size_t)(i * 64) * K,      smem + i * 512 * 8 + ldst);
        #pragma unroll
        for (int i = 0; i < 3; ++i) gload16(gb + (size_t)(i * 64) * K,      smem + G_ASZ + i * 512 * 8 + ldst);
        #pragma unroll
        for (int i = 0; i < 4; ++i) gload16(ga + (size_t)(i * 64) * K + 64, smem + G_STRIDE + i * 512 * 8 + ldst);
        #pragma unroll
        for (int i = 0; i < 3; ++i) gload16(gb + (size_t)(i * 64) * K + 64, smem + G_STRIDE + G_ASZ + i * 512 * 8 + ldst);
    }
    asm volatile("s_waitcnt vmcnt(7)" ::: "memory");
    __builtin_amdgcn_s_barrier();
    asm volatile("" ::: "memory");

    const int arow = (wr * 128 + l16) * 64;   // u16 offset of A frag row base
    const int brow = (wc * 48  + l16) * 64;
    const int rsw  = l16 & 7;

    for (int t = 0; t < NT; ++t) {
        const int boff = (t & 1) * G_STRIDE;
        const u16* as = smem + boff;
        const u16* bs = smem + boff + G_ASZ;
        #pragma unroll
        for (int ks = 0; ks < 2; ++ks) {
            const int ch = ((ks * 4 + quad) ^ rsw) * 8;
            short8 af[8], bfr[3];
            #pragma unroll
            for (int mf = 0; mf < 8; ++mf)
                af[mf] = *(const short8*)&as[arow + mf * (16 * 64) + ch];
            #pragma unroll
            for (int nf = 0; nf < 3; ++nf)
                bfr[nf] = *(const short8*)&bs[brow + nf * (16 * 64) + ch];
            #pragma unroll
            for (int mf = 0; mf < 8; ++mf)
                #pragma unroll
                for (int nf = 0; nf < 3; ++nf)
                    acc[mf][nf] = __builtin_amdgcn_mfma_f32_16x16x32_bf16(af[mf], bfr[nf], acc[mf][nf], 0, 0, 0);
        }
        if (t + 1 < NT) {
            asm volatile("s_waitcnt lgkmcnt(0)" ::: "memory");  // all my reads of buf[cur] done
            __builtin_amdgcn_s_barrier();                        // everyone done reading buf[cur]
            asm volatile("" ::: "memory");
            if (t + 2 < NT) {
                const int kk = (t + 2) * 64;
                u16* asw = smem + boff;          // stage tile t+2 into the buffer just freed
                u16* bsw = smem + boff + G_ASZ;
                #pragma unroll
                for (int i = 0; i < 4; ++i)
                    gload16(ga + (size_t)(i * 64) * K + kk, asw + i * 512 * 8 + ldst);
                #pragma unroll
                for (int i = 0; i < 3; ++i)
                    gload16(gb + (size_t)(i * 64) * K + kk, bsw + i * 512 * 8 + ldst);
                asm volatile("s_waitcnt vmcnt(7)" ::: "memory"); // tile t+1 landed; t+2 in flight
            } else {
                asm volatile("s_waitcnt vmcnt(0)" ::: "memory"); // tail drain
            }
            __builtin_amdgcn_s_barrier();                        // tile t+1 visible to all
            asm volatile("" ::: "memory");
        }
    }

    // epilogue: segmented bf16 store (q|k|v each [M][2048])
    #pragma unroll
    for (int mf = 0; mf < 8; ++mf)
        #pragma unroll
        for (int nf = 0; nf < 3; ++nf) {
            int col = n0 + wc * 48 + nf * 16 + l16;
            size_t base = ((size_t)(col >> 11) * M) * 2048 + (col & 2047);
            #pragma unroll
            for (int r = 0; r < 4; ++r) {
                int row = m0 + wr * 128 + mf * 16 + quad * 4 + r;
                Cv[base + (size_t)row * 2048] = f2bf(acc[mf][nf][r]);
            }
        }
}

// ---------------- GEMM: C[M][N] = A[M][K] * Bt[N][K]^T  (bf16 in, fp32 acc) ----------------
// 128^2 tile, register-staged, XOR-swizzled LDS. Kept for the output projection
// (N=2048 -> only 128 blocks at 256-tile, poor CU coverage; 512 blocks here).
template<int FP32OUT>
__global__ __launch_bounds__(256, 2) void gemm_bt_k(
    const u16* __restrict__ A, const u16* __restrict__ Bt, void* __restrict__ Cv,
    int M, int N, int K)
{
    __shared__ u16 As[128 * 64];
    __shared__ u16 Bs[128 * 64];
    const int tid = threadIdx.x, wave = tid >> 6, lane = tid & 63;
    const int quad = lane >> 4, l16 = lane & 15;
    const int m0 = blockIdx.y * 128, n0 = blockIdx.x * 128;
    const int mw = (wave & 1) * 64, nw = (wave >> 1) * 64;

    f32x4 zero = {0.f, 0.f, 0.f, 0.f};
    f32x4 acc[4][4];
    #pragma unroll
    for (int i = 0; i < 4; i++)
        #pragma unroll
        for (int j = 0; j < 4; j++) acc[i][j] = zero;

    const int sr = tid >> 3;          // 0..31
    const int sj = tid & 7;           // k-chunk
    const u16* ga0 = A  + (size_t)(m0 + sr) * K + sj * 8;
    const u16* gb0 = Bt + (size_t)(n0 + sr) * K + sj * 8;
    int woff[4];
    #pragma unroll
    for (int it = 0; it < 4; ++it) {
        int r = it * 32 + sr;
        woff[it] = r * 64 + ((sj ^ (r & 7)) * 8);
    }

    short8 abuf[4], bbuf[4];
    #pragma unroll
    for (int it = 0; it < 4; ++it) {
        abuf[it] = *(const short8*)(ga0 + (size_t)(it * 32) * K);
        bbuf[it] = *(const short8*)(gb0 + (size_t)(it * 32) * K);
    }
    #pragma unroll
    for (int it = 0; it < 4; ++it) {
        *(short8*)&As[woff[it]] = abuf[it];
        *(short8*)&Bs[woff[it]] = bbuf[it];
    }
    __syncthreads();

    const int rsw = l16 & 7;

    for (int kk = 0; kk < K; kk += 64) {
        const bool pre = (kk + 64 < K);
        if (pre) {
            #pragma unroll
            for (int it = 0; it < 4; ++it) {
                abuf[it] = *(const short8*)(ga0 + (size_t)(it * 32) * K + (kk + 64));
                bbuf[it] = *(const short8*)(gb0 + (size_t)(it * 32) * K + (kk + 64));
            }
        }
        #pragma unroll
        for (int ks = 0; ks < 2; ks++) {
            const int ch = ((ks * 4 + quad) ^ rsw) * 8;
            short8 af[4], bfr[4];
            #pragma unroll
            for (int mf = 0; mf < 4; mf++)
                af[mf] = *(const short8*)&As[(mw + mf * 16 + l16) * 64 + ch];
            #pragma unroll
            for (int nf = 0; nf < 4; nf++)
                bfr[nf] = *(const short8*)&Bs[(nw + nf * 16 + l16) * 64 + ch];
            #pragma unroll
            for (int mf = 0; mf < 4; mf++)
                #pragma unroll
                for (int nf = 0; nf < 4; nf++)
                    acc[mf][nf] = __builtin_amdgcn_mfma_f32_16x16x32_bf16(af[mf], bfr[nf], acc[mf][nf], 0, 0, 0);
        }
        if (pre) {
            __syncthreads();
            #pragma unroll
            for (int it = 0; it < 4; ++it) {
                *(short8*)&As[woff[it]] = abuf[it];
                *(short8*)&Bs[woff[it]] = bbuf[it];
            }
            __syncthreads();
        }
    }

    #pragma unroll
    for (int mf = 0; mf < 4; mf++)
        #pragma unroll
        for (int nf = 0; nf < 4; nf++)
            #pragma unroll
            for (int r = 0; r < 4; r++) {
                int row = m0 + mw + mf * 16 + quad * 4 + r;
                int col = n0 + nw + nf * 16 + l16;
                if (FP32OUT) ((float*)Cv)[(size_t)row * N + col] = acc[mf][nf][r];
                else         ((u16*) Cv)[(size_t)row * N + col] = f2bf(acc[mf][nf][r]);
            }
}

// ---------------- Flash attention, causal, paired complementary 64-row subtiles ----------------
__global__ __launch_bounds__(256, 2) void attn_k(
    const u16* __restrict__ q, const u16* __restrict__ k,
    const u16* __restrict__ vt, u16* __restrict__ o)
{
    __shared__ __align__(16) u16 Ks[64 * 132];   // [key][d], pad 4
    __shared__ __align__(16) u16 Vs[128 * 68];   // [d][key], pad 4 (= V^T)
    __shared__ __align__(16) u16 Pt[128 * 68];   // [qrow_local][key], pad 4
    const int tid = threadIdx.x, wave = tid >> 6, lane = tid & 63;
    const int quad = lane >> 4, l16 = lane & 15;
    const int h = blockIdx.y, b = blockIdx.z;
    const int p = (b & 1) ? (15 - (int)blockIdx.x) : (int)blockIdx.x;
    const int sub0 = p, sub1 = 31 - p;
    const int nkt = 32 - p;

    const int krow = tid >> 4, kc8 = tid & 15;
    const int vd   = tid >> 3, vc8 = tid & 7;
    const u16* kgp = k  + ((size_t)(b * AT_T) * AT_H + h) * 128;
    const u16* vgp = vt + ((size_t)(b * AT_H + h) * 128) * (size_t)AT_T;

    short8 qf[2][4];
    #pragma unroll
    for (int mf = 0; mf < 2; mf++) {
        int row = (mf ? sub1 : sub0) * 64 + wave * 16 + l16;
        const u16* qp = q + ((size_t)(b * AT_T + row) * AT_H + h) * 128 + quad * 8;
        #pragma unroll
        for (int ks = 0; ks < 4; ks++)
            qf[mf][ks] = *(const short8*)(qp + ks * 32);
    }

    f32x4 zero = {0.f, 0.f, 0.f, 0.f};
    f32x4 Oacc[2][8];
    #pragma unroll
    for (int i = 0; i < 2; i++)
        #pragma unroll
        for (int j = 0; j < 8; j++) Oacc[i][j] = zero;
    float l_i[2] = {0.f, 0.f};

    short8 kreg[4], vreg[4];
    #pragma unroll
    for (int it = 0; it < 4; ++it) {
        kreg[it] = *(const short8*)(kgp + (size_t)(krow + it * 16) * 2048 + kc8 * 8);
        vreg[it] = *(const short8*)(vgp + (size_t)(vd + it * 32) * AT_T + vc8 * 8);
    }
    #pragma unroll
    for (int it = 0; it < 4; ++it) {
        *(short8*)&Ks[(krow + it * 16) * 132 + kc8 * 8] = kreg[it];
        *(short8*)&Vs[(vd + it * 32) * 68 + vc8 * 8] = vreg[it];
    }
    __syncthreads();

    for (int kt = 0; kt < nkt; ++kt) {
        const bool pre = (kt + 1 < nkt);
        if (pre) {
            #pragma unroll
            for (int it = 0; it < 4; ++it) {
                kreg[it] = *(const short8*)(kgp + (size_t)((kt + 1) * 64 + krow + it * 16) * 2048 + kc8 * 8);
                vreg[it] = *(const short8*)(vgp + (size_t)(vd + it * 32) * AT_T + (kt + 1) * 64 + vc8 * 8);
            }
        }
        const bool actA = (kt <= sub0);

        f32x4 St[4][2];
        #pragma unroll
        for (int mt = 0; mt < 4; mt++) { St[mt][0] = zero; St[mt][1] = zero; }
        #pragma unroll
        for (int mt = 0; mt < 4; mt++) {
            short8 af[4];
            #pragma unroll
            for (int ks = 0; ks < 4; ks++)
                af[ks] = *(const short8*)&Ks[(mt * 16 + l16) * 132 + ks * 32 + quad * 8];
            #pragma unroll
            for (int ks = 0; ks < 4; ks++)
                St[mt][1] = __builtin_amdgcn_mfma_f32_16x16x32_bf16(af[ks], qf[1][ks], St[mt][1], 0, 0, 0);
            if (actA) {
                #pragma unroll
                for (int ks = 0; ks < 4; ks++)
                    St[mt][0] = __builtin_amdgcn_mfma_f32_16x16x32_bf16(af[ks], qf[0][ks], St[mt][0], 0, 0, 0);
            }
        }

        #pragma unroll
        for (int mf = 0; mf < 2; mf++) {
            if (mf == 0 && !actA) continue;
            const int sub = mf ? sub1 : sub0;
            if (kt == sub) {
                int qrow = sub * 64 + wave * 16 + l16;
                #pragma unroll
                for (int mt = 0; mt < 4; mt++)
                    #pragma unroll
                    for (int r = 0; r < 4; r++) {
                        int key = kt * 64 + mt * 16 + quad * 4 + r;
                        if (key > qrow) St[mt][mf][r] = -1e30f;
                    }
            }
            float rs = 0.f;
            #pragma unroll
            for (int mt = 0; mt < 4; mt++)
                #pragma unroll
                for (int r = 0; r < 4; r++) {
                    float pv = __expf(St[mt][mf][r]);
                    St[mt][mf][r] = pv;
                    rs += pv;
                }
            rs += __shfl_xor(rs, 16, 64);
            rs += __shfl_xor(rs, 32, 64);
            l_i[mf] += rs;
            u16* pp = &Pt[(mf * 64 + wave * 16 + l16) * 68 + quad * 4];
            #pragma unroll
            for (int mt = 0; mt < 4; mt++) {
                *(unsigned*)(pp + mt * 16)     = pack_bf2(St[mt][mf][0], St[mt][mf][1]);
                *(unsigned*)(pp + mt * 16 + 2) = pack_bf2(St[mt][mf][2], St[mt][mf][3]);
            }
        }

        short8 pf[2][2];
        #pragma unroll
        for (int mf = 0; mf < 2; mf++)
            #pragma unroll
            for (int ks = 0; ks < 2; ks++)
                pf[mf][ks] = *(const short8*)&Pt[(mf * 64 + wave * 16 + l16) * 68 + ks * 32 + quad * 8];

        #pragma unroll
        for (int mt = 0; mt < 8; mt++) {
            short8 vf[2];
            #pragma unroll
            for (int ks = 0; ks < 2; ks++)
                vf[ks] = *(const short8*)&Vs[(mt * 16 + l16) * 68 + ks * 32 + quad * 8];
            #pragma unroll
            for (int ks = 0; ks < 2; ks++) {
                Oacc[1][mt] = __builtin_amdgcn_mfma_f32_16x16x32_bf16(vf[ks], pf[1][ks], Oacc[1][mt], 0, 0, 0);
                if (actA)
                    Oacc[0][mt] = __builtin_amdgcn_mfma_f32_16x16x32_bf16(vf[ks], pf[0][ks], Oacc[0][mt], 0, 0, 0);
            }
        }

        __syncthreads();
        if (pre) {
            #pragma unroll
            for (int it = 0; it < 4; ++it) {
                *(short8*)&Ks[(krow + it * 16) * 132 + kc8 * 8] = kreg[it];
                *(short8*)&Vs[(vd + it * 32) * 68 + vc8 * 8] = vreg[it];
            }
        }
        __syncthreads();
    }

    #pragma unroll
    for (int mf = 0; mf < 2; mf++) {
        float inv = 1.0f / l_i[mf];
        int row = (mf ? sub1 : sub0) * 64 + wave * 16 + l16;
        u16* op = o + ((size_t)(b * AT_T + row) * AT_H + h) * 128 + quad * 4;
        #pragma unroll
        for (int mt = 0; mt < 8; mt++) {
            *(unsigned*)(op + mt * 16)     = pack_bf2(Oacc[mf][mt][0] * inv, Oacc[mf][mt][1] * inv);
            *(unsigned*)(op + mt * 16 + 2) = pack_bf2(Oacc[mf][mt][2] * inv, Oacc[mf][mt][3] * inv);
        }
    }
}

// ---------------- launch ----------------
extern "C" void kernel_launch(void* const* d_in, const int* in_sizes, int n_in,
                              void* d_out, int out_size, void* d_ws, size_t ws_size,
                              hipStream_t stream) {
    const float* x    = (const float*)d_in[0];
    const float* w_aq = (const float*)d_in[1];
    const float* w_ak = (const float*)d_in[2];
    const float* w_av = (const float*)d_in[3];
    const float* w_ao = (const float*)d_in[4];
    float* outp = (float*)d_out;

    u16* ws   = (u16*)d_ws;
    u16* xb   = ws;                           // [4096][2048]      x, bf16
    u16* wqb  = xb   + (size_t)NROW * HD;     // [6144 n][2048 k]  (wq|wk|wv transposed)
    u16* waob = wqb  + (size_t)3 * HD * AT_M; // [2048 m][2048 hd] (w_ao^T)
    u16* qb   = waob + (size_t)HD * AT_M;     // [B,T,H,D] (then kb, vb contiguous)
    u16* kb   = qb   + (size_t)NROW * HD;
    u16* vb   = kb   + (size_t)NROW * HD;
    u16* vtb  = vb   + (size_t)NROW * HD;     // [B,H,D,T]
    u16* ob   = xb;                           // alias: xb dead after projections

    // 1) casts / transposes
    cast_bf16_k<<<(NROW * HD / 4 + 255) / 256, 256, 0, stream>>>(x, xb, NROW * HD / 4);
    dim3 tb(32, 8);
    tcast3_k<<<dim3(AT_D / 32, AT_M / 32, 48), tb, 0, stream>>>(w_aq, w_ak, w_av, wqb);
    tcast_k<<<dim3(AT_M / 32, HD / 32), tb, 0, stream>>>(w_ao, waob, HD, AT_M);

    // 2) fused QKV projection: 256x192 tile, grid 32x16 = 512 blocks (2 full CU rounds)
    gemm256_qkv_k<<<dim3(3 * HD / 192, NROW / 256), 512, 0, stream>>>(xb, wqb, qb, NROW, 3 * HD, AT_M);

    // 3) RoPE on q,k (q scaled by 1/128)
    rope_k<<<(NROW * AT_H * 64 + 255) / 256, 256, 0, stream>>>(qb, kb, NROW * AT_H * 64);

    // 4) v -> [B,H,D,T]
    tbf16_k<<<dim3(HD / 32, AT_T / 32, AT_B), tb, 0, stream>>>(vb, vtb, AT_T, HD);

    // 5) attention (paired complementary subtiles, prefetch, max-free softmax)
    attn_k<<<dim3(16, AT_H, AT_B), 256, 0, stream>>>(qb, kb, vtb, ob);

    // 6) output projection (fp32 out)
    gemm_bt_k<1><<<dim3(AT_M / 128, NROW / 128), 256, 0, stream>>>(ob, waob, outp, NROW, AT_M, HD);
}